// Round 12
// baseline (84.558 us; speedup 1.0000x reference)
//
#include <hip/hip_runtime.h>
#include <math.h>

#define NN 8192
#define HH 128
#define LRELU_ALPHA 0.2f
#define R_ROWS 32           // rows with t_i >= 2^-32; truncation error < 2e-9
#define I0 (NN - R_ROWS)    // 8160
#define PBLK 128            // j-chunks
#define CJ 64               // j's per chunk

// u-prelude: compute u1 = W@a1, u2 = W@a2 into LDS (256 threads, 2 per k)
__device__ __forceinline__ void u_prelude(const float* __restrict__ W,
                                          const float* __restrict__ a,
                                          float* u1s, float* u2s, int tid) {
    int k = tid >> 1, half = tid & 1;
    const float4* wrow = (const float4*)(W + (size_t)k * HH + half * 64);
    const float4* a1v  = (const float4*)(a + half * 64);
    const float4* a2v  = (const float4*)(a + HH + half * 64);
    float p1 = 0.f, p2 = 0.f;
    #pragma unroll
    for (int q = 0; q < 16; q++) {
        float4 wv = wrow[q], b1 = a1v[q], b2 = a2v[q];
        p1 += wv.x * b1.x + wv.y * b1.y + wv.z * b1.z + wv.w * b1.w;
        p2 += wv.x * b2.x + wv.y * b2.y + wv.z * b2.z + wv.w * b2.w;
    }
    p1 += __shfl_xor(p1, 1);
    p2 += __shfl_xor(p2, 1);
    if (half == 0) { u1s[k] = p1; u2s[k] = p2; }
}

// ---------- K1: per 64-j chunk: e-tile, Zpart, y = e@inp, hW = y@W ----------
__global__ __launch_bounds__(256) void k_zy(const int* __restrict__ A,
                                            const float* __restrict__ inp,
                                            const float* __restrict__ W,
                                            const float* __restrict__ a,
                                            float* __restrict__ Zpart,
                                            float* __restrict__ hpartW) {
    const int p = blockIdx.x;            // 0..127
    const int jbase = p * CJ;
    const int tid = threadIdx.x;
    __shared__ float u1s[HH], u2s[HH];
    __shared__ float f1s[R_ROWS], f2s[CJ];
    __shared__ float es[R_ROWS][66];     // pad: 66 mod 32 = 2 -> ii spread over banks
    __shared__ float inpS[32][132];      // staging tile; reused for yS

    u_prelude(W, a, u1s, u2s, tid);
    __syncthreads();

    // f2s[jj] = inp[jbase+jj] @ u2  (4 threads per j, quarter dots)
    {
        int jj = tid >> 2, q = tid & 3;
        const float4* row = (const float4*)(inp + (size_t)(jbase + jj) * HH + q * 32);
        const float4* u2v = (const float4*)(u2s + q * 32);
        float acc = 0.f;
        #pragma unroll
        for (int t = 0; t < 8; t++) {
            float4 x = row[t], u = u2v[t];
            acc += x.x * u.x + x.y * u.y + x.z * u.z + x.w * u.w;
        }
        acc += __shfl_xor(acc, 1);
        acc += __shfl_xor(acc, 2);
        if (q == 0) f2s[jj] = acc;
    }
    // f1s (threads 0..31)
    if (tid < R_ROWS) {
        const float4* row = (const float4*)(inp + (size_t)(I0 + tid) * HH);
        const float4* u1v = (const float4*)u1s;
        float acc = 0.f;
        #pragma unroll
        for (int q = 0; q < 32; q++) {
            float4 x = row[q], u = u1v[q];
            acc += x.x * u.x + x.y * u.y + x.z * u.z + x.w * u.w;
        }
        f1s[tid] = acc;
    }
    __syncthreads();

    // e-tile + Zpart: thread (ii = tid>>3, s = tid&7), 8 j's each
    const int ii = tid >> 3, s = tid & 7;
    {
        const int i = I0 + ii;
        const int* arow = A + (size_t)i * NN + jbase + s * 8;
        const int4 a0 = *(const int4*)(arow);
        const int4 a1 = *(const int4*)(arow + 4);
        const int va[8] = {a0.x, a0.y, a0.z, a0.w, a1.x, a1.y, a1.z, a1.w};
        const float f1i = f1s[ii];
        float z = 0.f;
        #pragma unroll
        for (int c = 0; c < 8; c++) {
            int j = s * 8 + c;
            float x = f1i + f2s[j];
            x = x > 0.f ? x : LRELU_ALPHA * x;
            float ev = ((va[c] > 0) || (jbase + j == i)) ? __expf(x) : 0.f;
            es[ii][j] = ev;
            z += ev;
        }
        z += __shfl_xor(z, 1);
        z += __shfl_xor(z, 2);
        z += __shfl_xor(z, 4);
        if (s == 0) Zpart[(size_t)ii * PBLK + p] = z;
    }
    __syncthreads();

    // y-accum: y[ii][e0..e0+16) in registers, 2 inp tiles of 32 j's
    const int e0 = s * 16;
    float y[16];
    #pragma unroll
    for (int c = 0; c < 16; c++) y[c] = 0.f;

    #pragma unroll
    for (int tt = 0; tt < 2; ++tt) {
        {   // stage inpS[jj][0..128) <- inp[jbase + tt*32 + jj]
            int jj = tid >> 3, ch = tid & 7;
            const float4* src =
                (const float4*)(inp + (size_t)(jbase + tt * 32 + jj) * HH + ch * 16);
            float4* dst = (float4*)(&inpS[jj][ch * 16]);
            dst[0] = src[0]; dst[1] = src[1]; dst[2] = src[2]; dst[3] = src[3];
        }
        __syncthreads();
        for (int jj = 0; jj < 32; ++jj) {
            float ev = es[ii][tt * 32 + jj];
            const float4* iv = (const float4*)(&inpS[jj][e0]);
            float4 v0 = iv[0], v1 = iv[1], v2 = iv[2], v3 = iv[3];
            y[0]  += ev * v0.x; y[1]  += ev * v0.y; y[2]  += ev * v0.z; y[3]  += ev * v0.w;
            y[4]  += ev * v1.x; y[5]  += ev * v1.y; y[6]  += ev * v1.z; y[7]  += ev * v1.w;
            y[8]  += ev * v2.x; y[9]  += ev * v2.y; y[10] += ev * v2.z; y[11] += ev * v2.w;
            y[12] += ev * v3.x; y[13] += ev * v3.y; y[14] += ev * v3.z; y[15] += ev * v3.w;
        }
        __syncthreads();
    }

    // yS (reuse inpS): yS[ii][e0..+16) = y
    {
        float4* dst = (float4*)(&inpS[ii][e0]);
        dst[0] = make_float4(y[0],  y[1],  y[2],  y[3]);
        dst[1] = make_float4(y[4],  y[5],  y[6],  y[7]);
        dst[2] = make_float4(y[8],  y[9],  y[10], y[11]);
        dst[3] = make_float4(y[12], y[13], y[14], y[15]);
    }
    __syncthreads();

    // hW[ii][e0..+16) = sum_k yS[ii][k] * W[k][e0..+16)
    float hw[16];
    #pragma unroll
    for (int c = 0; c < 16; c++) hw[c] = 0.f;
    for (int k = 0; k < HH; ++k) {
        float yv = inpS[ii][k];
        const float4* wr = (const float4*)(W + (size_t)k * HH + e0);
        float4 w0 = wr[0], w1 = wr[1], w2 = wr[2], w3 = wr[3];
        hw[0]  += yv * w0.x; hw[1]  += yv * w0.y; hw[2]  += yv * w0.z; hw[3]  += yv * w0.w;
        hw[4]  += yv * w1.x; hw[5]  += yv * w1.y; hw[6]  += yv * w1.z; hw[7]  += yv * w1.w;
        hw[8]  += yv * w2.x; hw[9]  += yv * w2.y; hw[10] += yv * w2.z; hw[11] += yv * w2.w;
        hw[12] += yv * w3.x; hw[13] += yv * w3.y; hw[14] += yv * w3.z; hw[15] += yv * w3.w;
    }
    {
        float* dst = hpartW + ((size_t)p * R_ROWS + ii) * HH + e0;
        ((float4*)dst)[0] = make_float4(hw[0],  hw[1],  hw[2],  hw[3]);
        ((float4*)dst)[1] = make_float4(hw[4],  hw[5],  hw[6],  hw[7]);
        ((float4*)dst)[2] = make_float4(hw[8],  hw[9],  hw[10], hw[11]);
        ((float4*)dst)[3] = make_float4(hw[12], hw[13], hw[14], hw[15]);
    }
}

// ---------- K2: per 8-e' slice: h_t[e'] = sum_{p,ii} cz_ii hW[p][ii][e'], ELU --
__global__ __launch_bounds__(256) void k_fin(const float* __restrict__ Zpart,
                                             const float* __restrict__ hpartW,
                                             float* __restrict__ out) {
    const int m = blockIdx.x;            // 0..15, e'-slice m*8..+8
    const int tid = threadIdx.x;
    __shared__ float czs[R_ROWS];
    __shared__ float red[32][9];

    // czs[ii] = t_ii / Z_ii  (8 threads per ii over 128 Zpart entries)
    {
        int ii = tid >> 3, s = tid & 7;
        const float4* zp = (const float4*)(Zpart + (size_t)ii * PBLK + s * 16);
        float zs = 0.f;
        #pragma unroll
        for (int q = 0; q < 4; q++) {
            float4 zv = zp[q];
            zs += zv.x + zv.y + zv.z + zv.w;
        }
        zs += __shfl_xor(zs, 1);
        zs += __shfl_xor(zs, 2);
        zs += __shfl_xor(zs, 4);
        if (s == 0) czs[ii] = exp2f((float)(ii - R_ROWS)) / zs;
    }
    __syncthreads();

    const int c = tid & 7, g = tid >> 3;    // 32 groups x 8 e'-lanes
    float acc = 0.f;
    for (int idx = g; idx < PBLK * R_ROWS; idx += 32)
        acc += czs[idx & (R_ROWS - 1)] * hpartW[(size_t)idx * HH + m * 8 + c];
    red[g][c] = acc;
    __syncthreads();
    if (tid < 8) {
        float h = 0.f;
        #pragma unroll
        for (int gg = 0; gg < 32; gg++) h += red[gg][tid];
        h = h > 0.f ? h : expm1f(h);
        out[m * 8 + tid] = h;
    }
}

extern "C" void kernel_launch(void* const* d_in, const int* in_sizes, int n_in,
                              void* d_out, int out_size, void* d_ws, size_t ws_size,
                              hipStream_t stream) {
    const float* inp = (const float*)d_in[0];   // [8192,128] f32
    const int*   A   = (const int*)d_in[1];     // [8192,8192] i32
    const float* W   = (const float*)d_in[2];   // [128,128] f32
    const float* a   = (const float*)d_in[3];   // [256,1] f32
    float* out = (float*)d_out;                 // [128] f32
    float* ws  = (float*)d_ws;

    // workspace layout (floats)
    float* Zpart  = ws;                         // 32*128 = 4096
    float* hpartW = ws + 4096;                  // 128*32*128 = 524288 (2 MB)

    k_zy <<<PBLK, 256, 0, stream>>>(A, inp, W, a, Zpart, hpartW);
    k_fin<<<16,   256, 0, stream>>>(Zpart, hpartW, out);
}

// Round 13
// 26.253 us; speedup vs baseline: 3.2209x; 3.2209x over previous
//
#include <hip/hip_runtime.h>
#include <math.h>

#define NN 8192
#define HH 128
#define LRELU_ALPHA 0.2f
#define R_ROWS 16           // rows with t_i >= 2^-16; truncation error ~1e-4 << 7e-3
#define I0 (NN - R_ROWS)    // 8176
#define PBLK 128            // j-chunks (64 j's each)

// u-prelude: compute u1 = W@a1, u2 = W@a2 into LDS (256 threads, 2 per k)
__device__ __forceinline__ void u_prelude(const float* __restrict__ W,
                                          const float* __restrict__ a,
                                          float* u1s, float* u2s, int tid) {
    int k = tid >> 1, half = tid & 1;
    const float4* wrow = (const float4*)(W + (size_t)k * HH + half * 64);
    const float4* a1v  = (const float4*)(a + half * 64);
    const float4* a2v  = (const float4*)(a + HH + half * 64);
    float p1 = 0.f, p2 = 0.f;
    #pragma unroll
    for (int q = 0; q < 16; q++) {
        float4 wv = wrow[q], b1 = a1v[q], b2 = a2v[q];
        p1 += wv.x * b1.x + wv.y * b1.y + wv.z * b1.z + wv.w * b1.w;
        p2 += wv.x * b2.x + wv.y * b2.y + wv.z * b2.z + wv.w * b2.w;
    }
    p1 += __shfl_xor(p1, 1);
    p2 += __shfl_xor(p2, 1);
    if (half == 0) { u1s[k] = p1; u2s[k] = p2; }
}

// ---------- K1: per 64-j chunk: masked e^s tile + Zpart --------------------
// et[(p*16 + ii)*64 + jj] = masked exp(s_ij); Zpart[ii*PBLK + p] = partial Z
__global__ __launch_bounds__(256) void k_zw(const int* __restrict__ A,
                                            const float* __restrict__ inp,
                                            const float* __restrict__ W,
                                            const float* __restrict__ a,
                                            float* __restrict__ et,
                                            float* __restrict__ Zpart) {
    const int p = blockIdx.x;            // 0..127
    const int jbase = p * 64;
    const int tid = threadIdx.x;
    __shared__ float u1s[HH], u2s[HH];
    __shared__ float f1s[R_ROWS], f2s[64];

    u_prelude(W, a, u1s, u2s, tid);
    __syncthreads();

    // f2s[jj] = inp[jbase+jj] @ u2  (4 threads per j, quarter dots)
    {
        int jj = tid >> 2, q = tid & 3;
        const float4* row = (const float4*)(inp + (size_t)(jbase + jj) * HH + q * 32);
        const float4* u2v = (const float4*)(u2s + q * 32);
        float acc = 0.f;
        #pragma unroll
        for (int t = 0; t < 8; t++) {
            float4 x = row[t], u = u2v[t];
            acc += x.x * u.x + x.y * u.y + x.z * u.z + x.w * u.w;
        }
        acc += __shfl_xor(acc, 1);
        acc += __shfl_xor(acc, 2);
        if (q == 0) f2s[jj] = acc;
    }
    // f1s[r] = inp[I0+r] @ u1  (4 threads per row, 64 threads)
    if (tid < 4 * R_ROWS) {
        int r = tid >> 2, q = tid & 3;
        const float4* row = (const float4*)(inp + (size_t)(I0 + r) * HH + q * 32);
        const float4* u1v = (const float4*)(u1s + q * 32);
        float acc = 0.f;
        #pragma unroll
        for (int t = 0; t < 8; t++) {
            float4 x = row[t], u = u1v[t];
            acc += x.x * u.x + x.y * u.y + x.z * u.z + x.w * u.w;
        }
        acc += __shfl_xor(acc, 1);
        acc += __shfl_xor(acc, 2);
        if (q == 0) f1s[r] = acc;
    }
    __syncthreads();

    // e-tile: thread (ii = tid>>4, s = tid&15) handles 4 j's at s*4
    const int ii = tid >> 4, s = tid & 15;
    const int jj0 = s * 4;
    const int i = I0 + ii;
    const int4 av = *(const int4*)(A + (size_t)i * NN + jbase + jj0);
    const int va[4] = {av.x, av.y, av.z, av.w};
    const float f1i = f1s[ii];

    float e[4];
    float z = 0.f;
    #pragma unroll
    for (int c = 0; c < 4; c++) {
        float x = f1i + f2s[jj0 + c];
        x = x > 0.f ? x : LRELU_ALPHA * x;
        float ev = ((va[c] > 0) || (jbase + jj0 + c == i)) ? __expf(x) : 0.f;
        e[c] = ev;
        z += ev;
    }
    // 16-lane reduce for Zpart
    z += __shfl_xor(z, 1);
    z += __shfl_xor(z, 2);
    z += __shfl_xor(z, 4);
    z += __shfl_xor(z, 8);
    if (s == 0) Zpart[(size_t)ii * PBLK + p] = z;

    *(float4*)(et + ((size_t)p * R_ROWS + ii) * 64 + jj0) =
        make_float4(e[0], e[1], e[2], e[3]);
}

// ---------- K2: Z reduce -> w_j -> vfin -> hpart_b = vfin @ W -----------------
__global__ __launch_bounds__(256) void k_wv(const float* __restrict__ inp,
                                            const float* __restrict__ W,
                                            const float* __restrict__ et,
                                            const float* __restrict__ Zpart,
                                            float* __restrict__ hpart) {
    const int b = blockIdx.x;          // 128 blocks
    const int jbase = b * 64;
    const int tid = threadIdx.x;
    __shared__ float red[256];
    __shared__ float wj[64];
    __shared__ float czs[R_ROWS];
    __shared__ float vfin[128];

    // czs[ii] = t_ii / Z_ii  (16 threads per ii over 128 Zpart entries)
    {
        int ii = tid >> 4, s = tid & 15;
        const float4* zp = (const float4*)(Zpart + (size_t)ii * PBLK + s * 8);
        float4 z0 = zp[0], z1 = zp[1];
        float zsum = z0.x + z0.y + z0.z + z0.w + z1.x + z1.y + z1.z + z1.w;
        zsum += __shfl_xor(zsum, 1);
        zsum += __shfl_xor(zsum, 2);
        zsum += __shfl_xor(zsum, 4);
        zsum += __shfl_xor(zsum, 8);
        if (s == 0) czs[ii] = exp2f((float)(ii - R_ROWS)) / zsum;
    }
    __syncthreads();

    // w_j over 16 rows from the e-tile (4 i-groups x 64 j-lanes, 4 iterations)
    const int jj = tid & 63, ic = tid >> 6;
    float w = 0.f;
    #pragma unroll
    for (int q = 0; q < R_ROWS / 4; q++) {
        int ii = q * 4 + ic;
        w += czs[ii] * et[((size_t)b * R_ROWS + ii) * 64 + jj];
    }
    red[ic * 64 + jj] = w;
    __syncthreads();
    if (tid < 64) wj[tid] = red[tid] + red[64 + tid] + red[128 + tid] + red[192 + tid];
    __syncthreads();

    // weighted sum of inp rows for this j-range -> vfin[128]
    int k = tid & 127, half = tid >> 7;
    float v = 0.f;
    for (int j2 = half; j2 < 64; j2 += 2)
        v += wj[j2] * inp[(size_t)(jbase + j2) * HH + k];
    red[tid] = v;
    __syncthreads();
    if (half == 0) vfin[k] = red[k] + red[128 + k];
    __syncthreads();

    // hpart_b[e] = sum_k vfin[k] * W[k][e]
    float h = 0.f;
    for (int kk = half; kk < HH; kk += 2)
        h += vfin[kk] * W[(size_t)kk * HH + k];
    red[tid] = h;
    __syncthreads();
    if (half == 0) hpart[(size_t)b * HH + k] = red[k] + red[128 + k];
}

// ---------- K3: 16 blocks, block m: h_t[m*8..+8) = sum_b hpart_b, ELU ---------
__global__ __launch_bounds__(256) void k_final(const float* __restrict__ hpart,
                                               float* __restrict__ out) {
    const int m = blockIdx.x;            // 0..15
    const int tid = threadIdx.x;
    const int c = tid & 7, g = tid >> 3; // 32 groups x 8 e-lanes
    __shared__ float red[32][9];

    float acc = 0.f;
    #pragma unroll
    for (int b = g; b < 128; b += 32)
        acc += hpart[(size_t)b * HH + m * 8 + c];
    red[g][c] = acc;
    __syncthreads();
    if (tid < 8) {
        float h = 0.f;
        #pragma unroll
        for (int gg = 0; gg < 32; gg++) h += red[gg][tid];
        h = h > 0.f ? h : expm1f(h);
        out[m * 8 + tid] = h;
    }
}

extern "C" void kernel_launch(void* const* d_in, const int* in_sizes, int n_in,
                              void* d_out, int out_size, void* d_ws, size_t ws_size,
                              hipStream_t stream) {
    const float* inp = (const float*)d_in[0];   // [8192,128] f32
    const int*   A   = (const int*)d_in[1];     // [8192,8192] i32
    const float* W   = (const float*)d_in[2];   // [128,128] f32
    const float* a   = (const float*)d_in[3];   // [256,1] f32
    float* out = (float*)d_out;                 // [128] f32
    float* ws  = (float*)d_ws;

    // workspace layout (floats)
    float* Zpart = ws;                          // 16*128 = 2048
    float* et    = ws + 2048;                   // 128*16*64 = 131072 (512 KB)
    float* hpart = et + (size_t)PBLK * R_ROWS * 64;  // 128*128

    k_zw   <<<PBLK, 256, 0, stream>>>(A, inp, W, a, et, Zpart);
    k_wv   <<<PBLK, 256, 0, stream>>>(inp, W, et, Zpart, hpart);
    k_final<<<16,   256, 0, stream>>>(hpart, out);
}

// Round 14
// 23.860 us; speedup vs baseline: 3.5439x; 1.1003x over previous
//
#include <hip/hip_runtime.h>
#include <math.h>

#define NN 8192
#define HH 128
#define LRELU_ALPHA 0.2f
#define R_ROWS 16           // rows with t_i >= 2^-16; truncation error ~1e-4 << 7e-3
#define I0 (NN - R_ROWS)    // 8176
#define PBLK 128            // j-chunks (64 j's each)

// u-prelude: compute u1 = W@a1, u2 = W@a2 into LDS (256 threads, 2 per k)
__device__ __forceinline__ void u_prelude(const float* __restrict__ W,
                                          const float* __restrict__ a,
                                          float* u1s, float* u2s, int tid) {
    int k = tid >> 1, half = tid & 1;
    const float4* wrow = (const float4*)(W + (size_t)k * HH + half * 64);
    const float4* a1v  = (const float4*)(a + half * 64);
    const float4* a2v  = (const float4*)(a + HH + half * 64);
    float p1 = 0.f, p2 = 0.f;
    #pragma unroll
    for (int q = 0; q < 16; q++) {
        float4 wv = wrow[q], b1 = a1v[q], b2 = a2v[q];
        p1 += wv.x * b1.x + wv.y * b1.y + wv.z * b1.z + wv.w * b1.w;
        p2 += wv.x * b2.x + wv.y * b2.y + wv.z * b2.z + wv.w * b2.w;
    }
    p1 += __shfl_xor(p1, 1);
    p2 += __shfl_xor(p2, 1);
    if (half == 0) { u1s[k] = p1; u2s[k] = p2; }
}

// ---------- K1: per 64-j chunk: masked e^s tile + Zpart --------------------
// All independent global loads hoisted to kernel entry (latency overlap).
__global__ __launch_bounds__(256) void k_zw(const int* __restrict__ A,
                                            const float* __restrict__ inp,
                                            const float* __restrict__ W,
                                            const float* __restrict__ a,
                                            float* __restrict__ et,
                                            float* __restrict__ Zpart) {
    const int p = blockIdx.x;            // 0..127
    const int jbase = p * 64;
    const int tid = threadIdx.x;
    __shared__ float u1s[HH], u2s[HH];
    __shared__ float f1s[R_ROWS], f2s[64];

    // ---- early independent loads (issue before any barrier) ----
    const int ii = tid >> 4, s = tid & 15;          // e-tile coords
    const int i = I0 + ii;
    const int4 av = *(const int4*)(A + (size_t)i * NN + jbase + s * 4);

    const int jj2 = tid >> 2, q2 = tid & 3;         // f2 coords (4 thr/row)
    float4 fsrc[8];
    {
        const float4* row = (const float4*)(inp + (size_t)(jbase + jj2) * HH + q2 * 32);
        #pragma unroll
        for (int t = 0; t < 8; t++) fsrc[t] = row[t];
    }
    float4 f1src[8];
    if (tid < 4 * R_ROWS) {                         // f1 coords (4 thr/row)
        int r = tid >> 2, q = tid & 3;
        const float4* row = (const float4*)(inp + (size_t)(I0 + r) * HH + q * 32);
        #pragma unroll
        for (int t = 0; t < 8; t++) f1src[t] = row[t];
    }

    // u-compute (its W/a loads overlap the above in-flight loads)
    u_prelude(W, a, u1s, u2s, tid);
    __syncthreads();

    // f2s[jj2] = <fsrc, u2-quarter>
    {
        const float4* u2v = (const float4*)(u2s + q2 * 32);
        float acc = 0.f;
        #pragma unroll
        for (int t = 0; t < 8; t++) {
            float4 x = fsrc[t], u = u2v[t];
            acc += x.x * u.x + x.y * u.y + x.z * u.z + x.w * u.w;
        }
        acc += __shfl_xor(acc, 1);
        acc += __shfl_xor(acc, 2);
        if (q2 == 0) f2s[jj2] = acc;
    }
    if (tid < 4 * R_ROWS) {
        int r = tid >> 2, q = tid & 3;
        const float4* u1v = (const float4*)(u1s + q * 32);
        float acc = 0.f;
        #pragma unroll
        for (int t = 0; t < 8; t++) {
            float4 x = f1src[t], u = u1v[t];
            acc += x.x * u.x + x.y * u.y + x.z * u.z + x.w * u.w;
        }
        acc += __shfl_xor(acc, 1);
        acc += __shfl_xor(acc, 2);
        if (q == 0) f1s[r] = acc;
    }
    __syncthreads();

    // e-tile: thread (ii, s) handles 4 j's at s*4 (A already in av)
    const int jj0 = s * 4;
    const int va[4] = {av.x, av.y, av.z, av.w};
    const float f1i = f1s[ii];

    float e[4];
    float z = 0.f;
    #pragma unroll
    for (int c = 0; c < 4; c++) {
        float x = f1i + f2s[jj0 + c];
        x = x > 0.f ? x : LRELU_ALPHA * x;
        float ev = ((va[c] > 0) || (jbase + jj0 + c == i)) ? __expf(x) : 0.f;
        e[c] = ev;
        z += ev;
    }
    z += __shfl_xor(z, 1);
    z += __shfl_xor(z, 2);
    z += __shfl_xor(z, 4);
    z += __shfl_xor(z, 8);
    if (s == 0) Zpart[(size_t)ii * PBLK + p] = z;

    *(float4*)(et + ((size_t)p * R_ROWS + ii) * 64 + jj0) =
        make_float4(e[0], e[1], e[2], e[3]);
}

// ---------- K2: Z reduce -> w_j -> vfin -> hpart_b = vfin @ W -----------------
__global__ __launch_bounds__(256) void k_wv(const float* __restrict__ inp,
                                            const float* __restrict__ W,
                                            const float* __restrict__ et,
                                            const float* __restrict__ Zpart,
                                            float* __restrict__ hpart) {
    const int b = blockIdx.x;          // 128 blocks
    const int jbase = b * 64;
    const int tid = threadIdx.x;
    __shared__ float red[256];
    __shared__ float wj[64];
    __shared__ float czs[R_ROWS];
    __shared__ float vfin[128];

    // ---- early independent loads ----
    const int jj = tid & 63, ic = tid >> 6;         // w-gather coords
    float eg[R_ROWS / 4];
    #pragma unroll
    for (int q = 0; q < R_ROWS / 4; q++)
        eg[q] = et[((size_t)b * R_ROWS + q * 4 + ic) * 64 + jj];

    const int zii = tid >> 4, zs = tid & 15;        // Zpart coords
    const float4* zp = (const float4*)(Zpart + (size_t)zii * PBLK + zs * 8);
    float4 z0 = zp[0], z1 = zp[1];

    const int k = tid & 127, half = tid >> 7;       // vfin coords
    float isrc[32];
    #pragma unroll
    for (int idx = 0; idx < 32; idx++)
        isrc[idx] = inp[(size_t)(jbase + half + idx * 2) * HH + k];

    // czs[ii] = t_ii / Z_ii
    {
        float zsum = z0.x + z0.y + z0.z + z0.w + z1.x + z1.y + z1.z + z1.w;
        zsum += __shfl_xor(zsum, 1);
        zsum += __shfl_xor(zsum, 2);
        zsum += __shfl_xor(zsum, 4);
        zsum += __shfl_xor(zsum, 8);
        if (zs == 0) czs[zii] = exp2f((float)(zii - R_ROWS)) / zsum;
    }
    __syncthreads();

    // w_j over 16 rows from registers
    float w = 0.f;
    #pragma unroll
    for (int q = 0; q < R_ROWS / 4; q++)
        w += czs[q * 4 + ic] * eg[q];
    red[ic * 64 + jj] = w;
    __syncthreads();
    if (tid < 64) wj[tid] = red[tid] + red[64 + tid] + red[128 + tid] + red[192 + tid];
    __syncthreads();

    // weighted sum of inp rows (sources already in isrc)
    float v = 0.f;
    #pragma unroll
    for (int idx = 0; idx < 32; idx++)
        v += wj[half + idx * 2] * isrc[idx];
    red[tid] = v;
    __syncthreads();
    if (half == 0) vfin[k] = red[k] + red[128 + k];
    __syncthreads();

    // hpart_b[e] = sum_k vfin[k] * W[k][e]
    float h = 0.f;
    for (int kk = half; kk < HH; kk += 2)
        h += vfin[kk] * W[(size_t)kk * HH + k];
    red[tid] = h;
    __syncthreads();
    if (half == 0) hpart[(size_t)b * HH + k] = red[k] + red[128 + k];
}

// ---------- K3: 16 blocks, block m: h_t[m*8..+8) = sum_b hpart_b, ELU ---------
__global__ __launch_bounds__(256) void k_final(const float* __restrict__ hpart,
                                               float* __restrict__ out) {
    const int m = blockIdx.x;            // 0..15
    const int tid = threadIdx.x;
    const int c = tid & 7, g = tid >> 3; // 32 groups x 8 e-lanes
    __shared__ float red[32][9];

    float acc = 0.f;
    #pragma unroll
    for (int b = g; b < 128; b += 32)
        acc += hpart[(size_t)b * HH + m * 8 + c];
    red[g][c] = acc;
    __syncthreads();
    if (tid < 8) {
        float h = 0.f;
        #pragma unroll
        for (int gg = 0; gg < 32; gg++) h += red[gg][tid];
        h = h > 0.f ? h : expm1f(h);
        out[m * 8 + tid] = h;
    }
}

extern "C" void kernel_launch(void* const* d_in, const int* in_sizes, int n_in,
                              void* d_out, int out_size, void* d_ws, size_t ws_size,
                              hipStream_t stream) {
    const float* inp = (const float*)d_in[0];   // [8192,128] f32
    const int*   A   = (const int*)d_in[1];     // [8192,8192] i32
    const float* W   = (const float*)d_in[2];   // [128,128] f32
    const float* a   = (const float*)d_in[3];   // [256,1] f32
    float* out = (float*)d_out;                 // [128] f32
    float* ws  = (float*)d_ws;

    // workspace layout (floats)
    float* Zpart = ws;                          // 16*128 = 2048
    float* et    = ws + 2048;                   // 128*16*64 = 131072 (512 KB)
    float* hpart = et + (size_t)PBLK * R_ROWS * 64;  // 128*128

    k_zw   <<<PBLK, 256, 0, stream>>>(A, inp, W, a, et, Zpart);
    k_wv   <<<PBLK, 256, 0, stream>>>(inp, W, et, Zpart, hpart);
    k_final<<<16,   256, 0, stream>>>(hpart, out);
}

// Round 15
// 19.499 us; speedup vs baseline: 4.3365x; 1.2237x over previous
//
#include <hip/hip_runtime.h>
#include <math.h>

#define NN 8192
#define HH 128
#define LRELU_ALPHA 0.2f
#define R_ROWS 16           // rows with t_i >= 2^-16; truncation error ~1e-4 << 7e-3
#define I0 (NN - R_ROWS)    // 8176
#define PBLK 128            // j-chunks (64 j's each)

// ---------- K1 (512 thr): per 64-j chunk: masked e^s tile + Zpart -------------
__global__ __launch_bounds__(512) void k_zw(const int* __restrict__ A,
                                            const float* __restrict__ inp,
                                            const float* __restrict__ W,
                                            const float* __restrict__ a,
                                            float* __restrict__ et,
                                            float* __restrict__ Zpart) {
    const int p = blockIdx.x;            // 0..127
    const int jbase = p * 64;
    const int tid = threadIdx.x;
    __shared__ float u1s[HH], u2s[HH];
    __shared__ float f1s[R_ROWS], f2s[64];

    // ---- early independent loads (issue before any barrier) ----
    const int ii = tid >> 5, s = tid & 31;          // e-tile coords, 2 j's each
    const int i = I0 + ii;
    const int2 av = *(const int2*)(A + (size_t)i * NN + jbase + s * 2);

    const int jj2 = tid >> 3, q2 = tid & 7;         // f2 coords (8 thr/row)
    float4 fsrc[4];
    {
        const float4* row = (const float4*)(inp + (size_t)(jbase + jj2) * HH + q2 * 16);
        #pragma unroll
        for (int t = 0; t < 4; t++) fsrc[t] = row[t];
    }
    float4 f1src[4];
    if (tid < 8 * R_ROWS) {                         // f1 coords (8 thr/row)
        int r = tid >> 3, q = tid & 7;
        const float4* row = (const float4*)(inp + (size_t)(I0 + r) * HH + q * 16);
        #pragma unroll
        for (int t = 0; t < 4; t++) f1src[t] = row[t];
    }

    // u-compute: 4 threads per k, quarter-row dots
    {
        int k = tid >> 2, qu = tid & 3;
        const float4* wrow = (const float4*)(W + (size_t)k * HH + qu * 32);
        const float4* a1v  = (const float4*)(a + qu * 32);
        const float4* a2v  = (const float4*)(a + HH + qu * 32);
        float p1 = 0.f, p2 = 0.f;
        #pragma unroll
        for (int t = 0; t < 8; t++) {
            float4 wv = wrow[t], b1 = a1v[t], b2 = a2v[t];
            p1 += wv.x * b1.x + wv.y * b1.y + wv.z * b1.z + wv.w * b1.w;
            p2 += wv.x * b2.x + wv.y * b2.y + wv.z * b2.z + wv.w * b2.w;
        }
        p1 += __shfl_xor(p1, 1); p2 += __shfl_xor(p2, 1);
        p1 += __shfl_xor(p1, 2); p2 += __shfl_xor(p2, 2);
        if (qu == 0) { u1s[k] = p1; u2s[k] = p2; }
    }
    __syncthreads();

    // f2s[jj2] = <fsrc, u2-eighth>
    {
        const float4* u2v = (const float4*)(u2s + q2 * 16);
        float acc = 0.f;
        #pragma unroll
        for (int t = 0; t < 4; t++) {
            float4 x = fsrc[t], u = u2v[t];
            acc += x.x * u.x + x.y * u.y + x.z * u.z + x.w * u.w;
        }
        acc += __shfl_xor(acc, 1);
        acc += __shfl_xor(acc, 2);
        acc += __shfl_xor(acc, 4);
        if (q2 == 0) f2s[jj2] = acc;
    }
    if (tid < 8 * R_ROWS) {
        int r = tid >> 3, q = tid & 7;
        const float4* u1v = (const float4*)(u1s + q * 16);
        float acc = 0.f;
        #pragma unroll
        for (int t = 0; t < 4; t++) {
            float4 x = f1src[t], u = u1v[t];
            acc += x.x * u.x + x.y * u.y + x.z * u.z + x.w * u.w;
        }
        acc += __shfl_xor(acc, 1);
        acc += __shfl_xor(acc, 2);
        acc += __shfl_xor(acc, 4);
        if (q == 0) f1s[r] = acc;
    }
    __syncthreads();

    // e-tile: thread (ii, s) handles 2 j's at s*2 (A already in av)
    const int jj0 = s * 2;
    const float f1i = f1s[ii];

    float x0 = f1i + f2s[jj0];
    x0 = x0 > 0.f ? x0 : LRELU_ALPHA * x0;
    float e0 = ((av.x > 0) || (jbase + jj0 == i)) ? __expf(x0) : 0.f;
    float x1 = f1i + f2s[jj0 + 1];
    x1 = x1 > 0.f ? x1 : LRELU_ALPHA * x1;
    float e1 = ((av.y > 0) || (jbase + jj0 + 1 == i)) ? __expf(x1) : 0.f;

    float z = e0 + e1;
    z += __shfl_xor(z, 1);
    z += __shfl_xor(z, 2);
    z += __shfl_xor(z, 4);
    z += __shfl_xor(z, 8);
    z += __shfl_xor(z, 16);
    if (s == 0) Zpart[(size_t)ii * PBLK + p] = z;

    *(float2*)(et + ((size_t)p * R_ROWS + ii) * 64 + jj0) = make_float2(e0, e1);
}

// ---------- K2: Z reduce -> w_j -> vfin -> hpart_b = vfin @ W -----------------
__global__ __launch_bounds__(256) void k_wv(const float* __restrict__ inp,
                                            const float* __restrict__ W,
                                            const float* __restrict__ et,
                                            const float* __restrict__ Zpart,
                                            float* __restrict__ hpart) {
    const int b = blockIdx.x;          // 128 blocks
    const int jbase = b * 64;
    const int tid = threadIdx.x;
    __shared__ float red[256];
    __shared__ float wj[64];
    __shared__ float czs[R_ROWS];
    __shared__ float vfin[128];

    // ---- early independent loads ----
    const int jj = tid & 63, ic = tid >> 6;         // w-gather coords
    float eg[R_ROWS / 4];
    #pragma unroll
    for (int q = 0; q < R_ROWS / 4; q++)
        eg[q] = et[((size_t)b * R_ROWS + q * 4 + ic) * 64 + jj];

    const int zii = tid >> 4, zs = tid & 15;        // Zpart coords
    const float4* zp = (const float4*)(Zpart + (size_t)zii * PBLK + zs * 8);
    float4 z0 = zp[0], z1 = zp[1];

    const int k = tid & 127, half = tid >> 7;       // vfin / @W coords
    float isrc[32];
    #pragma unroll
    for (int idx = 0; idx < 32; idx++)
        isrc[idx] = inp[(size_t)(jbase + half + idx * 2) * HH + k];

    float w_reg[64];                                // hoisted W columns for @W
    #pragma unroll
    for (int idx = 0; idx < 64; idx++)
        w_reg[idx] = W[(size_t)(half + idx * 2) * HH + k];

    // czs[ii] = t_ii / Z_ii
    {
        float zsum = z0.x + z0.y + z0.z + z0.w + z1.x + z1.y + z1.z + z1.w;
        zsum += __shfl_xor(zsum, 1);
        zsum += __shfl_xor(zsum, 2);
        zsum += __shfl_xor(zsum, 4);
        zsum += __shfl_xor(zsum, 8);
        if (zs == 0) czs[zii] = exp2f((float)(zii - R_ROWS)) / zsum;
    }
    __syncthreads();

    // w_j over 16 rows from registers
    float w = 0.f;
    #pragma unroll
    for (int q = 0; q < R_ROWS / 4; q++)
        w += czs[q * 4 + ic] * eg[q];
    red[ic * 64 + jj] = w;
    __syncthreads();
    if (tid < 64) wj[tid] = red[tid] + red[64 + tid] + red[128 + tid] + red[192 + tid];
    __syncthreads();

    // weighted sum of inp rows (sources already in isrc)
    float v = 0.f;
    #pragma unroll
    for (int idx = 0; idx < 32; idx++)
        v += wj[half + idx * 2] * isrc[idx];
    red[tid] = v;
    __syncthreads();
    if (half == 0) vfin[k] = red[k] + red[128 + k];
    __syncthreads();

    // hpart_b[e] = sum_k vfin[k] * W[k][e]  (W already in w_reg)
    float h = 0.f;
    #pragma unroll
    for (int idx = 0; idx < 64; idx++)
        h += vfin[half + idx * 2] * w_reg[idx];
    red[tid] = h;
    __syncthreads();
    if (half == 0) hpart[(size_t)b * HH + k] = red[k] + red[128 + k];
}

// ---------- K3: 16 blocks, block m: h_t[m*8..+8) = sum_b hpart_b, ELU ---------
__global__ __launch_bounds__(256) void k_final(const float* __restrict__ hpart,
                                               float* __restrict__ out) {
    const int m = blockIdx.x;            // 0..15
    const int tid = threadIdx.x;
    const int c = tid & 7, g = tid >> 3; // 32 groups x 8 e-lanes
    __shared__ float red[32][9];

    float acc = 0.f;
    #pragma unroll
    for (int b = g; b < 128; b += 32)
        acc += hpart[(size_t)b * HH + m * 8 + c];
    red[g][c] = acc;
    __syncthreads();
    if (tid < 8) {
        float h = 0.f;
        #pragma unroll
        for (int gg = 0; gg < 32; gg++) h += red[gg][tid];
        h = h > 0.f ? h : expm1f(h);
        out[m * 8 + tid] = h;
    }
}

extern "C" void kernel_launch(void* const* d_in, const int* in_sizes, int n_in,
                              void* d_out, int out_size, void* d_ws, size_t ws_size,
                              hipStream_t stream) {
    const float* inp = (const float*)d_in[0];   // [8192,128] f32
    const int*   A   = (const int*)d_in[1];     // [8192,8192] i32
    const float* W   = (const float*)d_in[2];   // [128,128] f32
    const float* a   = (const float*)d_in[3];   // [256,1] f32
    float* out = (float*)d_out;                 // [128] f32
    float* ws  = (float*)d_ws;

    // workspace layout (floats)
    float* Zpart = ws;                          // 16*128 = 2048
    float* et    = ws + 2048;                   // 128*16*64 = 131072 (512 KB)
    float* hpart = et + (size_t)PBLK * R_ROWS * 64;  // 128*128

    k_zw   <<<PBLK, 512, 0, stream>>>(A, inp, W, a, et, Zpart);
    k_wv   <<<PBLK, 256, 0, stream>>>(inp, W, et, Zpart, hpart);
    k_final<<<16,   256, 0, stream>>>(hpart, out);
}

// Round 16
// 19.120 us; speedup vs baseline: 4.4224x; 1.0198x over previous
//
#include <hip/hip_runtime.h>
#include <math.h>

#define NN 8192
#define HH 128
#define LRELU_ALPHA 0.2f
#define R_ROWS 16           // rows with t_i >= 2^-16; truncation error ~1e-4 << 7e-3
#define I0 (NN - R_ROWS)    // 8176
#define PBLK 256            // j-chunks (32 j's each)
#define CJ 32               // j's per chunk

// ---------- K1 (256 blk x 512 thr): per 32-j chunk: masked e^s tile + Zpart ---
__global__ __launch_bounds__(512) void k_zw(const int* __restrict__ A,
                                            const float* __restrict__ inp,
                                            const float* __restrict__ W,
                                            const float* __restrict__ a,
                                            float* __restrict__ et,
                                            float* __restrict__ Zpart) {
    const int p = blockIdx.x;            // 0..255
    const int jbase = p * CJ;
    const int tid = threadIdx.x;
    __shared__ float u1s[HH], u2s[HH];
    __shared__ float f1s[R_ROWS], f2s[CJ];

    // ---- early independent loads (issue before any barrier) ----
    const int ii = tid >> 5, s = tid & 31;          // e-tile coords, 1 j each
    const int i = I0 + ii;
    const int av = A[(size_t)i * NN + jbase + s];

    const int jj2 = tid >> 4, q2 = tid & 15;        // f2 coords (16 thr/row)
    float4 fsrc[2];
    {
        const float4* row = (const float4*)(inp + (size_t)(jbase + jj2) * HH + q2 * 8);
        fsrc[0] = row[0]; fsrc[1] = row[1];
    }
    float4 f1src[4];
    if (tid < 8 * R_ROWS) {                         // f1 coords (8 thr/row)
        int r = tid >> 3, q = tid & 7;
        const float4* row = (const float4*)(inp + (size_t)(I0 + r) * HH + q * 16);
        #pragma unroll
        for (int t = 0; t < 4; t++) f1src[t] = row[t];
    }

    // u-compute: 4 threads per k, quarter-row dots
    {
        int k = tid >> 2, qu = tid & 3;
        const float4* wrow = (const float4*)(W + (size_t)k * HH + qu * 32);
        const float4* a1v  = (const float4*)(a + qu * 32);
        const float4* a2v  = (const float4*)(a + HH + qu * 32);
        float p1 = 0.f, p2 = 0.f;
        #pragma unroll
        for (int t = 0; t < 8; t++) {
            float4 wv = wrow[t], b1 = a1v[t], b2 = a2v[t];
            p1 += wv.x * b1.x + wv.y * b1.y + wv.z * b1.z + wv.w * b1.w;
            p2 += wv.x * b2.x + wv.y * b2.y + wv.z * b2.z + wv.w * b2.w;
        }
        p1 += __shfl_xor(p1, 1); p2 += __shfl_xor(p2, 1);
        p1 += __shfl_xor(p1, 2); p2 += __shfl_xor(p2, 2);
        if (qu == 0) { u1s[k] = p1; u2s[k] = p2; }
    }
    __syncthreads();

    // f2s[jj2] = <fsrc, u2[q2*8..+8)>
    {
        const float4* u2v = (const float4*)(u2s + q2 * 8);
        float4 x0 = fsrc[0], x1 = fsrc[1], u0 = u2v[0], u1 = u2v[1];
        float acc = x0.x * u0.x + x0.y * u0.y + x0.z * u0.z + x0.w * u0.w
                  + x1.x * u1.x + x1.y * u1.y + x1.z * u1.z + x1.w * u1.w;
        acc += __shfl_xor(acc, 1);
        acc += __shfl_xor(acc, 2);
        acc += __shfl_xor(acc, 4);
        acc += __shfl_xor(acc, 8);
        if (q2 == 0) f2s[jj2] = acc;
    }
    if (tid < 8 * R_ROWS) {
        int r = tid >> 3, q = tid & 7;
        const float4* u1v = (const float4*)(u1s + q * 16);
        float acc = 0.f;
        #pragma unroll
        for (int t = 0; t < 4; t++) {
            float4 x = f1src[t], u = u1v[t];
            acc += x.x * u.x + x.y * u.y + x.z * u.z + x.w * u.w;
        }
        acc += __shfl_xor(acc, 1);
        acc += __shfl_xor(acc, 2);
        acc += __shfl_xor(acc, 4);
        if (q == 0) f1s[r] = acc;
    }
    __syncthreads();

    // e-tile: thread (ii, s) handles 1 j (A already in av)
    float x0 = f1s[ii] + f2s[s];
    x0 = x0 > 0.f ? x0 : LRELU_ALPHA * x0;
    float e0 = ((av > 0) || (jbase + s == i)) ? __expf(x0) : 0.f;

    float z = e0;
    z += __shfl_xor(z, 1);
    z += __shfl_xor(z, 2);
    z += __shfl_xor(z, 4);
    z += __shfl_xor(z, 8);
    z += __shfl_xor(z, 16);
    if (s == 0) Zpart[(size_t)ii * PBLK + p] = z;

    et[((size_t)p * R_ROWS + ii) * CJ + s] = e0;
}

// ---------- K2 (256 blk x 512 thr): Z reduce -> w_j -> vfin -> @W -> hpart ----
__global__ __launch_bounds__(512) void k_wv(const float* __restrict__ inp,
                                            const float* __restrict__ W,
                                            const float* __restrict__ et,
                                            const float* __restrict__ Zpart,
                                            float* __restrict__ hpart) {
    const int b = blockIdx.x;          // 0..255
    const int jbase = b * CJ;
    const int tid = threadIdx.x;
    __shared__ float red[512];
    __shared__ float wj[CJ];
    __shared__ float czs[R_ROWS];
    __shared__ float vfin[128];

    // ---- early independent loads ----
    const int ic = tid >> 5, jj = tid & 31;         // w-gather coords (1 each)
    const float eg0 = et[((size_t)b * R_ROWS + ic) * CJ + jj];

    // Zpart: 32 threads per ii, 8 entries each (256 total)
    const float4* zp = (const float4*)(Zpart + (size_t)ic * PBLK + jj * 8);
    const float4 z0 = zp[0], z1 = zp[1];

    const int e = tid & 127, grp = tid >> 7;        // PV / @W coords
    float isrc[8];
    #pragma unroll
    for (int idx = 0; idx < 8; idx++)
        isrc[idx] = inp[(size_t)(jbase + grp + idx * 4) * HH + e];

    float w_reg[32];                                // hoisted W for @W
    #pragma unroll
    for (int idx = 0; idx < 32; idx++)
        w_reg[idx] = W[(size_t)(idx * 4 + grp) * HH + e];

    // czs[ii] = t_ii / Z_ii
    {
        float zsum = z0.x + z0.y + z0.z + z0.w + z1.x + z1.y + z1.z + z1.w;
        zsum += __shfl_xor(zsum, 1);
        zsum += __shfl_xor(zsum, 2);
        zsum += __shfl_xor(zsum, 4);
        zsum += __shfl_xor(zsum, 8);
        zsum += __shfl_xor(zsum, 16);
        if (jj == 0) czs[ic] = exp2f((float)(ic - R_ROWS)) / zsum;
    }
    __syncthreads();

    // w_j: per (ic, jj) one product, reduce over 16 ic
    red[ic * CJ + jj] = czs[ic] * eg0;
    __syncthreads();
    if (tid < CJ) {
        float s = 0.f;
        #pragma unroll
        for (int g = 0; g < R_ROWS; g++) s += red[g * CJ + tid];
        wj[tid] = s;
    }
    __syncthreads();

    // PV: vfin[e] = sum_j wj[j] * inp[jbase+j][e]
    float v = 0.f;
    #pragma unroll
    for (int idx = 0; idx < 8; idx++)
        v += wj[grp + idx * 4] * isrc[idx];
    red[tid] = v;
    __syncthreads();
    if (tid < 128) vfin[tid] = red[tid] + red[128 + tid] + red[256 + tid] + red[384 + tid];
    __syncthreads();

    // @W: hpart_b[e] = sum_k vfin[k] * W[k][e]
    float h = 0.f;
    #pragma unroll
    for (int idx = 0; idx < 32; idx++)
        h += vfin[idx * 4 + grp] * w_reg[idx];
    red[tid] = h;
    __syncthreads();
    if (tid < 128)
        hpart[(size_t)b * HH + tid] =
            red[tid] + red[128 + tid] + red[256 + tid] + red[384 + tid];
}

// ---------- K3: 16 blocks, block m: h_t[m*8..+8) = sum_b hpart_b, ELU ---------
__global__ __launch_bounds__(256) void k_final(const float* __restrict__ hpart,
                                               float* __restrict__ out) {
    const int m = blockIdx.x;            // 0..15
    const int tid = threadIdx.x;
    const int c = tid & 7, g = tid >> 3; // 32 groups x 8 e-lanes
    __shared__ float red[32][9];

    float acc = 0.f;
    #pragma unroll
    for (int b = g; b < PBLK; b += 32)
        acc += hpart[(size_t)b * HH + m * 8 + c];
    red[g][c] = acc;
    __syncthreads();
    if (tid < 8) {
        float h = 0.f;
        #pragma unroll
        for (int gg = 0; gg < 32; gg++) h += red[gg][tid];
        h = h > 0.f ? h : expm1f(h);
        out[m * 8 + tid] = h;
    }
}

extern "C" void kernel_launch(void* const* d_in, const int* in_sizes, int n_in,
                              void* d_out, int out_size, void* d_ws, size_t ws_size,
                              hipStream_t stream) {
    const float* inp = (const float*)d_in[0];   // [8192,128] f32
    const int*   A   = (const int*)d_in[1];     // [8192,8192] i32
    const float* W   = (const float*)d_in[2];   // [128,128] f32
    const float* a   = (const float*)d_in[3];   // [256,1] f32
    float* out = (float*)d_out;                 // [128] f32
    float* ws  = (float*)d_ws;

    // workspace layout (floats)
    float* Zpart = ws;                          // 16*256 = 4096
    float* et    = ws + 4096;                   // 256*16*32 = 131072 (512 KB)
    float* hpart = et + (size_t)PBLK * R_ROWS * CJ;  // 256*128

    k_zw   <<<PBLK, 512, 0, stream>>>(A, inp, W, a, et, Zpart);
    k_wv   <<<PBLK, 512, 0, stream>>>(inp, W, et, Zpart, hpart);
    k_final<<<16,   256, 0, stream>>>(hpart, out);
}